// Round 4
// baseline (496.442 us; speedup 1.0000x reference)
//
#include <hip/hip_runtime.h>
#include <hip/hip_bf16.h>

#define KOFF 27
#define C 64
#define EPS 1e-5f

typedef __attribute__((ext_vector_type(8))) short short8;
typedef __attribute__((ext_vector_type(4))) float f32x4;

__device__ inline unsigned short f2bf(float x) {
    __hip_bfloat16 h = __float2bfloat16(x);
    unsigned short u;
    __builtin_memcpy(&u, &h, 2);
    return u;
}

// ---- pre-pass 1: feats fp32 -> bf16 ----
__global__ void cvt_feats(const float* __restrict__ in, unsigned short* __restrict__ o, int n4) {
    int i = blockIdx.x * blockDim.x + threadIdx.x;
    if (i < n4) {
        float4 v = ((const float4*)in)[i];
        ushort4 u;
        u.x = f2bf(v.x); u.y = f2bf(v.y); u.z = f2bf(v.z); u.w = f2bf(v.w);
        ((ushort4*)o)[i] = u;
    }
}

// ---- pre-pass 2: W_conv & W_lin -> fragment-order bf16; zero-page ----
// frag layout: [t][ks][lane][j]: element (c = ks*32 + (lane>>4)*8 + j, d = t*16 + (lane&15))
__global__ void cvt_w(const float* __restrict__ Wc, const float* __restrict__ Wl,
                      unsigned short* __restrict__ WcF, unsigned short* __restrict__ WlF,
                      unsigned short* __restrict__ Z) {
    int i = blockIdx.x * blockDim.x + threadIdx.x;
    const int NWc = KOFF * 4096;
    if (i < NWc + 4096) {
        int rem = i & 4095;
        int t = rem >> 10;
        int ks = (rem >> 9) & 1;
        int l = (rem >> 3) & 63;
        int j = i & 7;
        int c = ks * 32 + ((l >> 4) << 3) + j;
        int d = (t << 4) + (l & 15);
        if (i < NWc) {
            int ko = i >> 12;
            WcF[i] = f2bf(Wc[(ko << 12) + (c << 6) + d]);
        } else {
            WlF[rem] = f2bf(Wl[(c << 6) + d]);
        }
    } else if (i < NWc + 4096 + 128) {
        Z[i - NWc - 4096] = 0;
    }
}

// ---- K3: global per-offset compaction ----
__global__ void build_pairs(const int* __restrict__ nb, int* __restrict__ cnt,
                            int2* __restrict__ pairs, int nvox) {
    int j = blockIdx.x * blockDim.x + threadIdx.x;
    if (j >= nvox * KOFF) return;
    int ko = j % KOFF;
    int r = j / KOFF;
    if (ko == 13) return;                // self handled by dense pass
    int src = nb[j];
    if (src >= 0) {
        int pos = atomicAdd(&cnt[ko], 1);
        pairs[(size_t)ko * nvox + pos] = make_int2(src, r);
    }
}

// ---- K4: dense self GEMM, initializes d_out = feats @ W13 + b_conv ----
__launch_bounds__(256)
__global__ void self_gemm(const unsigned short* __restrict__ feats,
                          const unsigned short* __restrict__ WcF,
                          const float* __restrict__ b_conv,
                          float* __restrict__ out, int nvox) {
    const int tid = threadIdx.x;
    const int lane = tid & 63;
    const int wave = tid >> 6;
    const int m = lane & 15;
    const int krow = lane >> 4;
    const int coff = krow * 8;

    const int rb = blockIdx.x * 128 + wave * 32 + m;
    const int r0 = min(rb, nvox - 1);
    const int r1 = min(rb + 16, nvox - 1);

    short8 a00 = *(const short8*)(feats + (size_t)r0 * C + coff);
    short8 a01 = *(const short8*)(feats + (size_t)r0 * C + 32 + coff);
    short8 a10 = *(const short8*)(feats + (size_t)r1 * C + coff);
    short8 a11 = *(const short8*)(feats + (size_t)r1 * C + 32 + coff);

    const unsigned short* w13 = WcF + 13 * 4096 + lane * 8;
    f32x4 c0[4], c1[4];
#pragma unroll
    for (int t = 0; t < 4; ++t) {
        c0[t] = (f32x4){0.f, 0.f, 0.f, 0.f};
        c1[t] = (f32x4){0.f, 0.f, 0.f, 0.f};
    }
#pragma unroll
    for (int t = 0; t < 4; ++t) {
        short8 b0 = *(const short8*)(w13 + t * 1024);
        short8 b1 = *(const short8*)(w13 + t * 1024 + 512);
        c0[t] = __builtin_amdgcn_mfma_f32_16x16x32_bf16(a00, b0, c0[t], 0, 0, 0);
        c0[t] = __builtin_amdgcn_mfma_f32_16x16x32_bf16(a01, b1, c0[t], 0, 0, 0);
        c1[t] = __builtin_amdgcn_mfma_f32_16x16x32_bf16(a10, b0, c1[t], 0, 0, 0);
        c1[t] = __builtin_amdgcn_mfma_f32_16x16x32_bf16(a11, b1, c1[t], 0, 0, 0);
    }

    float bc[4];
#pragma unroll
    for (int t = 0; t < 4; ++t) bc[t] = b_conv[t * 16 + m];

#pragma unroll
    for (int rbk = 0; rbk < 2; ++rbk) {
        f32x4* c = rbk ? c1 : c0;
#pragma unroll
        for (int i = 0; i < 4; ++i) {
            int grow = blockIdx.x * 128 + wave * 32 + rbk * 16 + krow * 4 + i;
            if (grow < nvox) {
#pragma unroll
                for (int t = 0; t < 4; ++t)
                    out[(size_t)grow * C + t * 16 + m] = c[t][i] + bc[t];
            }
        }
    }
}

// ---- K5: sparse scatter tiles, global atomicAdd into d_out ----
__launch_bounds__(256)
__global__ void scatter_conv(const unsigned short* __restrict__ feats,
                             const unsigned short* __restrict__ WcF,
                             const unsigned short* __restrict__ zpage,
                             const int* __restrict__ cnt,
                             const int2* __restrict__ pairs,
                             float* __restrict__ out, int nvox, int nwaves) {
    const int tid = threadIdx.x;
    const int lane = tid & 63;
    const int wave = tid >> 6;
    const int m = lane & 15;
    const int krow = lane >> 4;
    const int coff = krow * 8;
    const int gw = blockIdx.x * 4 + wave;

    // per-wave tile-space prefix over the 26 sparse offsets
    int c = (lane < KOFF && lane != 13) ? cnt[lane] : 0;
    int tiles = (c + 15) >> 4;
    int pre = tiles;
#pragma unroll
    for (int d = 1; d < 32; d <<= 1) {
        int v = __shfl_up(pre, d, 64);
        if (lane >= d) pre += v;
    }
    const int total = __shfl(pre, KOFF - 1, 64);
    const int base_l = pre - tiles;

    for (int t = gw; t < total; t += nwaves) {
        unsigned long long msk = __ballot(lane < KOFF && base_l <= t && t < pre);
        int ko = __ffsll(msk) - 1;
        int base = __shfl(base_l, ko, 64);
        int cko = __shfl(c, ko, 64);
        int s0 = (t - base) * 16;

        int slot = s0 + m;
        int src = -1, dst = -1;
        if (slot < cko) {
            int2 e = pairs[(size_t)ko * nvox + slot];
            src = e.x;
            dst = e.y;
        }
        const unsigned short* pa = (src >= 0) ? feats + ((size_t)src << 6) : zpage;
        short8 a0 = *(const short8*)(pa + coff);
        short8 a1 = *(const short8*)(pa + 32 + coff);

        int dsts[4];
#pragma unroll
        for (int i = 0; i < 4; ++i)
            dsts[i] = __shfl(dst, (lane & 48) + krow * 4 + i, 64);

        const unsigned short* w = WcF + ((size_t)ko << 12) + lane * 8;
        f32x4 c4[4];
#pragma unroll
        for (int t4 = 0; t4 < 4; ++t4) {
            short8 b0 = *(const short8*)(w + t4 * 1024);
            short8 b1 = *(const short8*)(w + t4 * 1024 + 512);
            c4[t4] = (f32x4){0.f, 0.f, 0.f, 0.f};
            c4[t4] = __builtin_amdgcn_mfma_f32_16x16x32_bf16(a0, b0, c4[t4], 0, 0, 0);
            c4[t4] = __builtin_amdgcn_mfma_f32_16x16x32_bf16(a1, b1, c4[t4], 0, 0, 0);
        }
#pragma unroll
        for (int t4 = 0; t4 < 4; ++t4)
#pragma unroll
            for (int i = 0; i < 4; ++i)
                if (dsts[i] >= 0)
                    atomicAdd(out + (size_t)dsts[i] * C + t4 * 16 + m, c4[t4][i]);
    }
}

// ---- K6: linear + LayerNorm, in-place on d_out (wave-local rows) ----
__launch_bounds__(256)
__global__ void lin_ln(const float* xin,
                       const unsigned short* __restrict__ WlF,
                       const float* __restrict__ b_lin,
                       const float* __restrict__ gamma,
                       const float* __restrict__ beta,
                       float* out, int nvox) {
    const int tid = threadIdx.x;
    const int lane = tid & 63;
    const int wave = tid >> 6;
    const int m = lane & 15;
    const int krow = lane >> 4;
    const int coff = krow * 8;

    const int rb = blockIdx.x * 128 + wave * 32 + m;
    const int r0 = min(rb, nvox - 1);
    const int r1 = min(rb + 16, nvox - 1);

    auto ldx = [&](int r, int ks) -> short8 {
        const float* p = xin + (size_t)r * C + ks * 32 + coff;
        float4 x0 = *(const float4*)p;
        float4 x1 = *(const float4*)(p + 4);
        short8 v;
        v[0] = (short)f2bf(x0.x); v[1] = (short)f2bf(x0.y);
        v[2] = (short)f2bf(x0.z); v[3] = (short)f2bf(x0.w);
        v[4] = (short)f2bf(x1.x); v[5] = (short)f2bf(x1.y);
        v[6] = (short)f2bf(x1.z); v[7] = (short)f2bf(x1.w);
        return v;
    };
    short8 xa00 = ldx(r0, 0), xa01 = ldx(r0, 1);
    short8 xa10 = ldx(r1, 0), xa11 = ldx(r1, 1);

    f32x4 d0[4], d1[4];
#pragma unroll
    for (int t = 0; t < 4; ++t) {
        d0[t] = (f32x4){0.f, 0.f, 0.f, 0.f};
        d1[t] = (f32x4){0.f, 0.f, 0.f, 0.f};
    }
    const unsigned short* wl = WlF + lane * 8;
#pragma unroll
    for (int t = 0; t < 4; ++t) {
        short8 wb0 = *(const short8*)(wl + t * 1024);
        short8 wb1 = *(const short8*)(wl + t * 1024 + 512);
        d0[t] = __builtin_amdgcn_mfma_f32_16x16x32_bf16(xa00, wb0, d0[t], 0, 0, 0);
        d0[t] = __builtin_amdgcn_mfma_f32_16x16x32_bf16(xa01, wb1, d0[t], 0, 0, 0);
        d1[t] = __builtin_amdgcn_mfma_f32_16x16x32_bf16(xa10, wb0, d1[t], 0, 0, 0);
        d1[t] = __builtin_amdgcn_mfma_f32_16x16x32_bf16(xa11, wb1, d1[t], 0, 0, 0);
    }

    float bl[4], g4[4], bt[4];
#pragma unroll
    for (int t = 0; t < 4; ++t) {
        int col = t * 16 + m;
        bl[t] = b_lin[col];
        g4[t] = gamma[col];
        bt[t] = beta[col];
    }

#pragma unroll
    for (int rbk = 0; rbk < 2; ++rbk) {
        f32x4* d = rbk ? d1 : d0;
        float s1[4], s2[4];
#pragma unroll
        for (int i = 0; i < 4; ++i) {
            float a0 = d[0][i] + bl[0];
            float a1 = d[1][i] + bl[1];
            float a2 = d[2][i] + bl[2];
            float a3 = d[3][i] + bl[3];
            d[0][i] = a0; d[1][i] = a1; d[2][i] = a2; d[3][i] = a3;
            s1[i] = a0 + a1 + a2 + a3;
            s2[i] = a0 * a0 + a1 * a1 + a2 * a2 + a3 * a3;
        }
#pragma unroll
        for (int msk = 1; msk < 16; msk <<= 1) {
#pragma unroll
            for (int i = 0; i < 4; ++i) {
                s1[i] += __shfl_xor(s1[i], msk, 64);
                s2[i] += __shfl_xor(s2[i], msk, 64);
            }
        }
#pragma unroll
        for (int i = 0; i < 4; ++i) {
            float mu = s1[i] * (1.f / 64.f);
            float var = s2[i] * (1.f / 64.f) - mu * mu;
            float rs = rsqrtf(var + EPS);
            int grow = blockIdx.x * 128 + wave * 32 + rbk * 16 + krow * 4 + i;
            if (grow < nvox) {
#pragma unroll
                for (int t = 0; t < 4; ++t)
                    out[(size_t)grow * C + t * 16 + m] = g4[t] * (d[t][i] - mu) * rs + bt[t];
            }
        }
    }
}

extern "C" void kernel_launch(void* const* d_in, const int* in_sizes, int n_in,
                              void* d_out, int out_size, void* d_ws, size_t ws_size,
                              hipStream_t stream) {
    const float* feats = (const float*)d_in[0];
    const int* nb = (const int*)d_in[1];
    const float* Wc = (const float*)d_in[2];
    const float* b_conv = (const float*)d_in[3];
    const float* Wl = (const float*)d_in[4];
    const float* b_lin = (const float*)d_in[5];
    const float* gamma = (const float*)d_in[6];
    const float* beta = (const float*)d_in[7];
    float* out = (float*)d_out;

    const int nvox = in_sizes[0] / C;

    // ws layout (byte offsets, aligned)
    char* ws = (char*)d_ws;
    unsigned short* feats_bf = (unsigned short*)ws;                    // 2*nvox*64
    size_t off = (size_t)nvox * C * 2;
    unsigned short* WcF = (unsigned short*)(ws + off); off += KOFF * 4096 * 2;
    unsigned short* WlF = (unsigned short*)(ws + off); off += 4096 * 2;
    unsigned short* Z = (unsigned short*)(ws + off);   off += 256;
    off = (off + 255) & ~(size_t)255;
    int* cnt = (int*)(ws + off);                        off += 128;
    off = (off + 255) & ~(size_t)255;
    int2* pairs = (int2*)(ws + off);

    hipMemsetAsync(cnt, 0, KOFF * sizeof(int), stream);

    int n4 = (nvox * C) / 4;
    cvt_feats<<<(n4 + 255) / 256, 256, 0, stream>>>(feats, feats_bf, n4);

    int nw = KOFF * 4096 + 4096 + 128;
    cvt_w<<<(nw + 255) / 256, 256, 0, stream>>>(Wc, Wl, WcF, WlF, Z);

    int nj = nvox * KOFF;
    build_pairs<<<(nj + 255) / 256, 256, 0, stream>>>(nb, cnt, pairs, nvox);

    int nblk = (nvox + 127) / 128;
    self_gemm<<<nblk, 256, 0, stream>>>(feats_bf, WcF, b_conv, out, nvox);

    const int NB5 = 2048;
    scatter_conv<<<NB5, 256, 0, stream>>>(feats_bf, WcF, Z, cnt, pairs, out, nvox, NB5 * 4);

    lin_ln<<<nblk, 256, 0, stream>>>(out, WlF, b_lin, gamma, beta, out, nvox);
}

// Round 5
// 89.857 us; speedup vs baseline: 5.5248x; 5.5248x over previous
//
#include <hip/hip_runtime.h>
#include <hip/hip_bf16.h>

#define KOFF 27
#define C 64
#define EPS 1e-5f

typedef __attribute__((ext_vector_type(8))) short short8;
typedef __attribute__((ext_vector_type(4))) float f32x4;

__device__ inline unsigned short f2bf(float x) {
    __hip_bfloat16 h = __float2bfloat16(x);
    unsigned short u;
    __builtin_memcpy(&u, &h, 2);
    return u;
}

// ---- pre-pass 1: feats fp32 -> bf16 ----
__global__ void cvt_feats(const float* __restrict__ in, unsigned short* __restrict__ o, int n4) {
    int i = blockIdx.x * blockDim.x + threadIdx.x;
    if (i < n4) {
        float4 v = ((const float4*)in)[i];
        ushort4 u;
        u.x = f2bf(v.x); u.y = f2bf(v.y); u.z = f2bf(v.z); u.w = f2bf(v.w);
        ((ushort4*)o)[i] = u;
    }
}

// ---- pre-pass 2: W_conv & W_lin -> fragment-order bf16; zero-page ----
// frag layout: [t][ks][lane][j]: element (c = ks*32 + (lane>>4)*8 + j, d = t*16 + (lane&15))
__global__ void cvt_w(const float* __restrict__ Wc, const float* __restrict__ Wl,
                      unsigned short* __restrict__ WcF, unsigned short* __restrict__ WlF,
                      unsigned short* __restrict__ Z) {
    int i = blockIdx.x * blockDim.x + threadIdx.x;
    const int NWc = KOFF * 4096;
    if (i < NWc + 4096) {
        int rem = i & 4095;
        int t = rem >> 10;
        int ks = (rem >> 9) & 1;
        int l = (rem >> 3) & 63;
        int j = i & 7;
        int c = ks * 32 + ((l >> 4) << 3) + j;
        int d = (t << 4) + (l & 15);
        if (i < NWc) {
            int ko = i >> 12;
            WcF[i] = f2bf(Wc[(ko << 12) + (c << 6) + d]);
        } else {
            WlF[rem] = f2bf(Wl[(c << 6) + d]);
        }
    } else if (i < NWc + 4096 + 128) {
        Z[i - NWc - 4096] = 0;
    }
}

// ---- K3: block-aggregated per-offset compaction (few atomics) ----
// cnt is padded: counter for ko lives at cnt[ko*16] (one 64B line each).
__launch_bounds__(256)
__global__ void build_pairs(const int* __restrict__ nb, int* __restrict__ cnt,
                            int2* __restrict__ pairs, int nvox) {
    __shared__ int lds_nb[256 * KOFF];
    __shared__ int wcnt[KOFF][4];
    __shared__ int gbase[KOFF];

    const int tid = threadIdx.x;
    const int lane = tid & 63;
    const int wave = tid >> 6;
    const int row0 = blockIdx.x * 256;

    // coalesced stage of 256 rows x 27 indices
    {
        const long gb = (long)row0 * KOFF;
        const long glim = (long)nvox * KOFF;
        for (int j = tid; j < 256 * KOFF; j += 256) {
            long g = gb + j;
            lds_nb[j] = (g < glim) ? nb[g] : -1;
        }
    }
    __syncthreads();

    // phase A: per-wave counts per offset (no barriers inside)
    const unsigned long long lmask = (1ull << lane) - 1;
#pragma unroll
    for (int ko = 0; ko < KOFF; ++ko) {
        if (ko == 13) continue;
        int src = lds_nb[tid * KOFF + ko];
        unsigned long long msk = __ballot(src >= 0);
        if (lane == 0) wcnt[ko][wave] = __popcll(msk);
    }
    __syncthreads();

    // phase B: 26 parallel atomics (one per offset) from the first wave
    if (tid < KOFF && tid != 13) {
        int tot = wcnt[tid][0] + wcnt[tid][1] + wcnt[tid][2] + wcnt[tid][3];
        gbase[tid] = atomicAdd(&cnt[tid * 16], tot);
    }
    __syncthreads();

    // phase C: write compacted pairs
#pragma unroll
    for (int ko = 0; ko < KOFF; ++ko) {
        if (ko == 13) continue;
        int src = lds_nb[tid * KOFF + ko];
        unsigned long long msk = __ballot(src >= 0);
        int pre = __popcll(msk & lmask);
        int wb = 0;
#pragma unroll
        for (int w = 0; w < 4; ++w)
            if (w < wave) wb += wcnt[ko][w];
        if (src >= 0)
            pairs[(size_t)ko * nvox + gbase[ko] + wb + pre] =
                make_int2(src, row0 + tid);
    }
}

// ---- K4: dense self GEMM, initializes d_out = feats @ W13 + b_conv ----
__launch_bounds__(256)
__global__ void self_gemm(const unsigned short* __restrict__ feats,
                          const unsigned short* __restrict__ WcF,
                          const float* __restrict__ b_conv,
                          float* __restrict__ out, int nvox) {
    const int tid = threadIdx.x;
    const int lane = tid & 63;
    const int wave = tid >> 6;
    const int m = lane & 15;
    const int krow = lane >> 4;
    const int coff = krow * 8;

    const int rb = blockIdx.x * 128 + wave * 32 + m;
    const int r0 = min(rb, nvox - 1);
    const int r1 = min(rb + 16, nvox - 1);

    short8 a00 = *(const short8*)(feats + (size_t)r0 * C + coff);
    short8 a01 = *(const short8*)(feats + (size_t)r0 * C + 32 + coff);
    short8 a10 = *(const short8*)(feats + (size_t)r1 * C + coff);
    short8 a11 = *(const short8*)(feats + (size_t)r1 * C + 32 + coff);

    const unsigned short* w13 = WcF + 13 * 4096 + lane * 8;
    f32x4 c0[4], c1[4];
#pragma unroll
    for (int t = 0; t < 4; ++t) {
        c0[t] = (f32x4){0.f, 0.f, 0.f, 0.f};
        c1[t] = (f32x4){0.f, 0.f, 0.f, 0.f};
    }
#pragma unroll
    for (int t = 0; t < 4; ++t) {
        short8 b0 = *(const short8*)(w13 + t * 1024);
        short8 b1 = *(const short8*)(w13 + t * 1024 + 512);
        c0[t] = __builtin_amdgcn_mfma_f32_16x16x32_bf16(a00, b0, c0[t], 0, 0, 0);
        c0[t] = __builtin_amdgcn_mfma_f32_16x16x32_bf16(a01, b1, c0[t], 0, 0, 0);
        c1[t] = __builtin_amdgcn_mfma_f32_16x16x32_bf16(a10, b0, c1[t], 0, 0, 0);
        c1[t] = __builtin_amdgcn_mfma_f32_16x16x32_bf16(a11, b1, c1[t], 0, 0, 0);
    }

    float bc[4];
#pragma unroll
    for (int t = 0; t < 4; ++t) bc[t] = b_conv[t * 16 + m];

#pragma unroll
    for (int rbk = 0; rbk < 2; ++rbk) {
        f32x4* c = rbk ? c1 : c0;
#pragma unroll
        for (int i = 0; i < 4; ++i) {
            int grow = blockIdx.x * 128 + wave * 32 + rbk * 16 + krow * 4 + i;
            if (grow < nvox) {
#pragma unroll
                for (int t = 0; t < 4; ++t)
                    out[(size_t)grow * C + t * 16 + m] = c[t][i] + bc[t];
            }
        }
    }
}

// ---- K5: sparse scatter tiles, global atomicAdd into d_out ----
__launch_bounds__(256)
__global__ void scatter_conv(const unsigned short* __restrict__ feats,
                             const unsigned short* __restrict__ WcF,
                             const unsigned short* __restrict__ zpage,
                             const int* __restrict__ cnt,
                             const int2* __restrict__ pairs,
                             float* __restrict__ out, int nvox, int nwaves) {
    const int tid = threadIdx.x;
    const int lane = tid & 63;
    const int wave = tid >> 6;
    const int m = lane & 15;
    const int krow = lane >> 4;
    const int coff = krow * 8;
    const int gw = blockIdx.x * 4 + wave;

    // per-wave tile-space prefix over the 26 sparse offsets
    int c = (lane < KOFF && lane != 13) ? cnt[lane * 16] : 0;
    int tiles = (c + 15) >> 4;
    int pre = tiles;
#pragma unroll
    for (int d = 1; d < 32; d <<= 1) {
        int v = __shfl_up(pre, d, 64);
        if (lane >= d) pre += v;
    }
    const int total = __shfl(pre, KOFF - 1, 64);
    const int base_l = pre - tiles;

    for (int t = gw; t < total; t += nwaves) {
        unsigned long long msk = __ballot(lane < KOFF && base_l <= t && t < pre);
        int ko = __ffsll(msk) - 1;
        int base = __shfl(base_l, ko, 64);
        int cko = __shfl(c, ko, 64);
        int s0 = (t - base) * 16;

        int slot = s0 + m;
        int src = -1, dst = -1;
        if (slot < cko) {
            int2 e = pairs[(size_t)ko * nvox + slot];
            src = e.x;
            dst = e.y;
        }
        const unsigned short* pa = (src >= 0) ? feats + ((size_t)src << 6) : zpage;
        short8 a0 = *(const short8*)(pa + coff);
        short8 a1 = *(const short8*)(pa + 32 + coff);

        int dsts[4];
#pragma unroll
        for (int i = 0; i < 4; ++i)
            dsts[i] = __shfl(dst, (lane & 48) + krow * 4 + i, 64);

        const unsigned short* w = WcF + ((size_t)ko << 12) + lane * 8;
        f32x4 c4[4];
#pragma unroll
        for (int t4 = 0; t4 < 4; ++t4) {
            short8 b0 = *(const short8*)(w + t4 * 1024);
            short8 b1 = *(const short8*)(w + t4 * 1024 + 512);
            c4[t4] = (f32x4){0.f, 0.f, 0.f, 0.f};
            c4[t4] = __builtin_amdgcn_mfma_f32_16x16x32_bf16(a0, b0, c4[t4], 0, 0, 0);
            c4[t4] = __builtin_amdgcn_mfma_f32_16x16x32_bf16(a1, b1, c4[t4], 0, 0, 0);
        }
#pragma unroll
        for (int t4 = 0; t4 < 4; ++t4)
#pragma unroll
            for (int i = 0; i < 4; ++i)
                if (dsts[i] >= 0)
                    atomicAdd(out + (size_t)dsts[i] * C + t4 * 16 + m, c4[t4][i]);
    }
}

// ---- K6: linear + LayerNorm, in-place on d_out (wave-local rows) ----
__launch_bounds__(256)
__global__ void lin_ln(const float* xin,
                       const unsigned short* __restrict__ WlF,
                       const float* __restrict__ b_lin,
                       const float* __restrict__ gamma,
                       const float* __restrict__ beta,
                       float* out, int nvox) {
    const int tid = threadIdx.x;
    const int lane = tid & 63;
    const int wave = tid >> 6;
    const int m = lane & 15;
    const int krow = lane >> 4;
    const int coff = krow * 8;

    const int rb = blockIdx.x * 128 + wave * 32 + m;
    const int r0 = min(rb, nvox - 1);
    const int r1 = min(rb + 16, nvox - 1);

    auto ldx = [&](int r, int ks) -> short8 {
        const float* p = xin + (size_t)r * C + ks * 32 + coff;
        float4 x0 = *(const float4*)p;
        float4 x1 = *(const float4*)(p + 4);
        short8 v;
        v[0] = (short)f2bf(x0.x); v[1] = (short)f2bf(x0.y);
        v[2] = (short)f2bf(x0.z); v[3] = (short)f2bf(x0.w);
        v[4] = (short)f2bf(x1.x); v[5] = (short)f2bf(x1.y);
        v[6] = (short)f2bf(x1.z); v[7] = (short)f2bf(x1.w);
        return v;
    };
    short8 xa00 = ldx(r0, 0), xa01 = ldx(r0, 1);
    short8 xa10 = ldx(r1, 0), xa11 = ldx(r1, 1);

    f32x4 d0[4], d1[4];
#pragma unroll
    for (int t = 0; t < 4; ++t) {
        d0[t] = (f32x4){0.f, 0.f, 0.f, 0.f};
        d1[t] = (f32x4){0.f, 0.f, 0.f, 0.f};
    }
    const unsigned short* wl = WlF + lane * 8;
#pragma unroll
    for (int t = 0; t < 4; ++t) {
        short8 wb0 = *(const short8*)(wl + t * 1024);
        short8 wb1 = *(const short8*)(wl + t * 1024 + 512);
        d0[t] = __builtin_amdgcn_mfma_f32_16x16x32_bf16(xa00, wb0, d0[t], 0, 0, 0);
        d0[t] = __builtin_amdgcn_mfma_f32_16x16x32_bf16(xa01, wb1, d0[t], 0, 0, 0);
        d1[t] = __builtin_amdgcn_mfma_f32_16x16x32_bf16(xa10, wb0, d1[t], 0, 0, 0);
        d1[t] = __builtin_amdgcn_mfma_f32_16x16x32_bf16(xa11, wb1, d1[t], 0, 0, 0);
    }

    float bl[4], g4[4], bt[4];
#pragma unroll
    for (int t = 0; t < 4; ++t) {
        int col = t * 16 + m;
        bl[t] = b_lin[col];
        g4[t] = gamma[col];
        bt[t] = beta[col];
    }

#pragma unroll
    for (int rbk = 0; rbk < 2; ++rbk) {
        f32x4* d = rbk ? d1 : d0;
        float s1[4], s2[4];
#pragma unroll
        for (int i = 0; i < 4; ++i) {
            float a0 = d[0][i] + bl[0];
            float a1 = d[1][i] + bl[1];
            float a2 = d[2][i] + bl[2];
            float a3 = d[3][i] + bl[3];
            d[0][i] = a0; d[1][i] = a1; d[2][i] = a2; d[3][i] = a3;
            s1[i] = a0 + a1 + a2 + a3;
            s2[i] = a0 * a0 + a1 * a1 + a2 * a2 + a3 * a3;
        }
#pragma unroll
        for (int msk = 1; msk < 16; msk <<= 1) {
#pragma unroll
            for (int i = 0; i < 4; ++i) {
                s1[i] += __shfl_xor(s1[i], msk, 64);
                s2[i] += __shfl_xor(s2[i], msk, 64);
            }
        }
#pragma unroll
        for (int i = 0; i < 4; ++i) {
            float mu = s1[i] * (1.f / 64.f);
            float var = s2[i] * (1.f / 64.f) - mu * mu;
            float rs = rsqrtf(var + EPS);
            int grow = blockIdx.x * 128 + wave * 32 + rbk * 16 + krow * 4 + i;
            if (grow < nvox) {
#pragma unroll
                for (int t = 0; t < 4; ++t)
                    out[(size_t)grow * C + t * 16 + m] = g4[t] * (d[t][i] - mu) * rs + bt[t];
            }
        }
    }
}

extern "C" void kernel_launch(void* const* d_in, const int* in_sizes, int n_in,
                              void* d_out, int out_size, void* d_ws, size_t ws_size,
                              hipStream_t stream) {
    const float* feats = (const float*)d_in[0];
    const int* nb = (const int*)d_in[1];
    const float* Wc = (const float*)d_in[2];
    const float* b_conv = (const float*)d_in[3];
    const float* Wl = (const float*)d_in[4];
    const float* b_lin = (const float*)d_in[5];
    const float* gamma = (const float*)d_in[6];
    const float* beta = (const float*)d_in[7];
    float* out = (float*)d_out;

    const int nvox = in_sizes[0] / C;

    // ws layout (byte offsets, aligned)
    char* ws = (char*)d_ws;
    unsigned short* feats_bf = (unsigned short*)ws;                    // 2*nvox*64
    size_t off = (size_t)nvox * C * 2;
    unsigned short* WcF = (unsigned short*)(ws + off); off += KOFF * 4096 * 2;
    unsigned short* WlF = (unsigned short*)(ws + off); off += 4096 * 2;
    unsigned short* Z = (unsigned short*)(ws + off);   off += 256;
    off = (off + 255) & ~(size_t)255;
    int* cnt = (int*)(ws + off);                        off += KOFF * 16 * 4;
    off = (off + 255) & ~(size_t)255;
    int2* pairs = (int2*)(ws + off);

    hipMemsetAsync(cnt, 0, KOFF * 16 * sizeof(int), stream);

    int n4 = (nvox * C) / 4;
    cvt_feats<<<(n4 + 255) / 256, 256, 0, stream>>>(feats, feats_bf, n4);

    int nw = KOFF * 4096 + 4096 + 128;
    cvt_w<<<(nw + 255) / 256, 256, 0, stream>>>(Wc, Wl, WcF, WlF, Z);

    int nblk_b = (nvox + 255) / 256;
    build_pairs<<<nblk_b, 256, 0, stream>>>(nb, cnt, pairs, nvox);

    int nblk = (nvox + 127) / 128;
    self_gemm<<<nblk, 256, 0, stream>>>(feats_bf, WcF, b_conv, out, nvox);

    const int NB5 = 2048;
    scatter_conv<<<NB5, 256, 0, stream>>>(feats_bf, WcF, Z, cnt, pairs, out, nvox, NB5 * 4);

    lin_ln<<<nblk, 256, 0, stream>>>(out, WlF, b_lin, gamma, beta, out, nvox);
}

// Round 6
// 89.364 us; speedup vs baseline: 5.5553x; 1.0055x over previous
//
#include <hip/hip_runtime.h>
#include <hip/hip_bf16.h>

#define KOFF 27
#define C 64
#define EPS 1e-5f
#define PER 8   // scan elems per lane; supports up to 512 blocks (nvox <= 131072)

typedef __attribute__((ext_vector_type(8))) short short8;
typedef __attribute__((ext_vector_type(4))) float f32x4;

__device__ inline unsigned short f2bf(float x) {
    __hip_bfloat16 h = __float2bfloat16(x);
    unsigned short u;
    __builtin_memcpy(&u, &h, 2);
    return u;
}

// ---- pre-pass 1: feats fp32 -> bf16 ----
__global__ void cvt_feats(const float* __restrict__ in, unsigned short* __restrict__ o, int n4) {
    int i = blockIdx.x * blockDim.x + threadIdx.x;
    if (i < n4) {
        float4 v = ((const float4*)in)[i];
        ushort4 u;
        u.x = f2bf(v.x); u.y = f2bf(v.y); u.z = f2bf(v.z); u.w = f2bf(v.w);
        ((ushort4*)o)[i] = u;
    }
}

// ---- pre-pass 2: W_conv & W_lin -> fragment-order bf16; zero-page ----
// frag layout: [t][ks][lane][j]: element (c = ks*32 + (lane>>4)*8 + j, d = t*16 + (lane&15))
__global__ void cvt_w(const float* __restrict__ Wc, const float* __restrict__ Wl,
                      unsigned short* __restrict__ WcF, unsigned short* __restrict__ WlF,
                      unsigned short* __restrict__ Z) {
    int i = blockIdx.x * blockDim.x + threadIdx.x;
    const int NWc = KOFF * 4096;
    if (i < NWc + 4096) {
        int rem = i & 4095;
        int t = rem >> 10;
        int ks = (rem >> 9) & 1;
        int l = (rem >> 3) & 63;
        int j = i & 7;
        int c = ks * 32 + ((l >> 4) << 3) + j;
        int d = (t << 4) + (l & 15);
        if (i < NWc) {
            int ko = i >> 12;
            WcF[i] = f2bf(Wc[(ko << 12) + (c << 6) + d]);
        } else {
            WlF[rem] = f2bf(Wl[(c << 6) + d]);
        }
    } else if (i < NWc + 4096 + 128) {
        Z[i - NWc - 4096] = 0;
    }
}

// ---- K3a: per-block per-offset counts (no atomics) ----
__launch_bounds__(256)
__global__ void count_pairs(const int* __restrict__ nb, int* __restrict__ cnt_blk, int nvox) {
    __shared__ int lds_nb[256 * KOFF];
    __shared__ int wcnt[KOFF][4];
    const int tid = threadIdx.x;
    const int lane = tid & 63;
    const int wave = tid >> 6;
    const int row0 = blockIdx.x * 256;
    {
        const long gb = (long)row0 * KOFF;
        const long glim = (long)nvox * KOFF;
        for (int j = tid; j < 256 * KOFF; j += 256) {
            long g = gb + j;
            lds_nb[j] = (g < glim) ? nb[g] : -1;
        }
    }
    __syncthreads();
#pragma unroll
    for (int ko = 0; ko < KOFF; ++ko) {
        if (ko == 13) continue;
        int src = lds_nb[tid * KOFF + ko];
        unsigned long long msk = __ballot(src >= 0);
        if (lane == 0) wcnt[ko][wave] = __popcll(msk);
    }
    __syncthreads();
    if (tid < KOFF)
        cnt_blk[blockIdx.x * 32 + tid] =
            (tid == 13) ? 0 : (wcnt[tid][0] + wcnt[tid][1] + wcnt[tid][2] + wcnt[tid][3]);
}

// ---- K3b: exclusive scan over blocks, per offset (27 blocks x 1 wave) ----
__launch_bounds__(64)
__global__ void scan_pairs(const int* __restrict__ cnt_blk, int* __restrict__ blk_base,
                           int* __restrict__ tot, int nblk) {
    const int ko = blockIdx.x;
    const int lane = threadIdx.x;
    const int base = lane * PER;
    int loc[PER];
    int sum = 0;
#pragma unroll
    for (int i = 0; i < PER; ++i) {
        int idx = base + i;
        int v = (idx < nblk) ? cnt_blk[idx * 32 + ko] : 0;
        loc[i] = sum;
        sum += v;
    }
    int incl = sum;
#pragma unroll
    for (int d = 1; d < 64; d <<= 1) {
        int v = __shfl_up(incl, d, 64);
        if (lane >= d) incl += v;
    }
    int excl = incl - sum;
#pragma unroll
    for (int i = 0; i < PER; ++i) {
        int idx = base + i;
        if (idx < nblk) blk_base[idx * 32 + ko] = excl + loc[i];
    }
    if (lane == 63) tot[ko] = incl;
}

// ---- K3c: write compacted pairs at deterministic offsets ----
__launch_bounds__(256)
__global__ void write_pairs(const int* __restrict__ nb, const int* __restrict__ blk_base,
                            int2* __restrict__ pairs, int nvox) {
    __shared__ int lds_nb[256 * KOFF];
    __shared__ int wcnt[KOFF][4];
    const int tid = threadIdx.x;
    const int lane = tid & 63;
    const int wave = tid >> 6;
    const int row0 = blockIdx.x * 256;
    {
        const long gb = (long)row0 * KOFF;
        const long glim = (long)nvox * KOFF;
        for (int j = tid; j < 256 * KOFF; j += 256) {
            long g = gb + j;
            lds_nb[j] = (g < glim) ? nb[g] : -1;
        }
    }
    __syncthreads();
    const unsigned long long lmask = (1ull << lane) - 1;
#pragma unroll
    for (int ko = 0; ko < KOFF; ++ko) {
        if (ko == 13) continue;
        int src = lds_nb[tid * KOFF + ko];
        unsigned long long msk = __ballot(src >= 0);
        if (lane == 0) wcnt[ko][wave] = __popcll(msk);
    }
    __syncthreads();
#pragma unroll
    for (int ko = 0; ko < KOFF; ++ko) {
        if (ko == 13) continue;
        int src = lds_nb[tid * KOFF + ko];
        unsigned long long msk = __ballot(src >= 0);
        int pre = __popcll(msk & lmask);
        int wb = 0;
#pragma unroll
        for (int w = 0; w < 4; ++w)
            if (w < wave) wb += wcnt[ko][w];
        if (src >= 0)
            pairs[(size_t)ko * nvox + blk_base[blockIdx.x * 32 + ko] + wb + pre] =
                make_int2(src, row0 + tid);
    }
}

// ---- K4: dense self GEMM, initializes d_out = feats @ W13 + b_conv ----
__launch_bounds__(256)
__global__ void self_gemm(const unsigned short* __restrict__ feats,
                          const unsigned short* __restrict__ WcF,
                          const float* __restrict__ b_conv,
                          float* __restrict__ out, int nvox) {
    const int tid = threadIdx.x;
    const int lane = tid & 63;
    const int wave = tid >> 6;
    const int m = lane & 15;
    const int krow = lane >> 4;
    const int coff = krow * 8;

    const int rb = blockIdx.x * 128 + wave * 32 + m;
    const int r0 = min(rb, nvox - 1);
    const int r1 = min(rb + 16, nvox - 1);

    short8 a00 = *(const short8*)(feats + (size_t)r0 * C + coff);
    short8 a01 = *(const short8*)(feats + (size_t)r0 * C + 32 + coff);
    short8 a10 = *(const short8*)(feats + (size_t)r1 * C + coff);
    short8 a11 = *(const short8*)(feats + (size_t)r1 * C + 32 + coff);

    const unsigned short* w13 = WcF + 13 * 4096 + lane * 8;
    f32x4 c0[4], c1[4];
#pragma unroll
    for (int t = 0; t < 4; ++t) {
        c0[t] = (f32x4){0.f, 0.f, 0.f, 0.f};
        c1[t] = (f32x4){0.f, 0.f, 0.f, 0.f};
    }
#pragma unroll
    for (int t = 0; t < 4; ++t) {
        short8 b0 = *(const short8*)(w13 + t * 1024);
        short8 b1 = *(const short8*)(w13 + t * 1024 + 512);
        c0[t] = __builtin_amdgcn_mfma_f32_16x16x32_bf16(a00, b0, c0[t], 0, 0, 0);
        c0[t] = __builtin_amdgcn_mfma_f32_16x16x32_bf16(a01, b1, c0[t], 0, 0, 0);
        c1[t] = __builtin_amdgcn_mfma_f32_16x16x32_bf16(a10, b0, c1[t], 0, 0, 0);
        c1[t] = __builtin_amdgcn_mfma_f32_16x16x32_bf16(a11, b1, c1[t], 0, 0, 0);
    }

    float bc[4];
#pragma unroll
    for (int t = 0; t < 4; ++t) bc[t] = b_conv[t * 16 + m];

#pragma unroll
    for (int rbk = 0; rbk < 2; ++rbk) {
        f32x4* c = rbk ? c1 : c0;
#pragma unroll
        for (int i = 0; i < 4; ++i) {
            int grow = blockIdx.x * 128 + wave * 32 + rbk * 16 + krow * 4 + i;
            if (grow < nvox) {
#pragma unroll
                for (int t = 0; t < 4; ++t)
                    out[(size_t)grow * C + t * 16 + m] = c[t][i] + bc[t];
            }
        }
    }
}

// ---- K5: sparse scatter tiles, global atomicAdd into d_out ----
__launch_bounds__(256)
__global__ void scatter_conv(const unsigned short* __restrict__ feats,
                             const unsigned short* __restrict__ WcF,
                             const unsigned short* __restrict__ zpage,
                             const int* __restrict__ tot,
                             const int2* __restrict__ pairs,
                             float* __restrict__ out, int nvox, int nwaves) {
    const int tid = threadIdx.x;
    const int lane = tid & 63;
    const int wave = tid >> 6;
    const int m = lane & 15;
    const int krow = lane >> 4;
    const int coff = krow * 8;
    const int gw = blockIdx.x * 4 + wave;

    // per-wave tile-space prefix over the 26 sparse offsets
    int c = (lane < KOFF && lane != 13) ? tot[lane] : 0;
    int tiles = (c + 15) >> 4;
    int pre = tiles;
#pragma unroll
    for (int d = 1; d < 32; d <<= 1) {
        int v = __shfl_up(pre, d, 64);
        if (lane >= d) pre += v;
    }
    const int total = __shfl(pre, KOFF - 1, 64);
    const int base_l = pre - tiles;

    for (int t = gw; t < total; t += nwaves) {
        unsigned long long msk = __ballot(lane < KOFF && base_l <= t && t < pre);
        int ko = __ffsll(msk) - 1;
        int base = __shfl(base_l, ko, 64);
        int cko = __shfl(c, ko, 64);
        int s0 = (t - base) * 16;

        int slot = s0 + m;
        int src = -1, dst = -1;
        if (slot < cko) {
            int2 e = pairs[(size_t)ko * nvox + slot];
            src = e.x;
            dst = e.y;
        }
        const unsigned short* pa = (src >= 0) ? feats + ((size_t)src << 6) : zpage;
        short8 a0 = *(const short8*)(pa + coff);
        short8 a1 = *(const short8*)(pa + 32 + coff);

        int dsts[4];
#pragma unroll
        for (int i = 0; i < 4; ++i)
            dsts[i] = __shfl(dst, (lane & 48) + krow * 4 + i, 64);

        const unsigned short* w = WcF + ((size_t)ko << 12) + lane * 8;
        f32x4 c4[4];
#pragma unroll
        for (int t4 = 0; t4 < 4; ++t4) {
            short8 b0 = *(const short8*)(w + t4 * 1024);
            short8 b1 = *(const short8*)(w + t4 * 1024 + 512);
            c4[t4] = (f32x4){0.f, 0.f, 0.f, 0.f};
            c4[t4] = __builtin_amdgcn_mfma_f32_16x16x32_bf16(a0, b0, c4[t4], 0, 0, 0);
            c4[t4] = __builtin_amdgcn_mfma_f32_16x16x32_bf16(a1, b1, c4[t4], 0, 0, 0);
        }
#pragma unroll
        for (int t4 = 0; t4 < 4; ++t4)
#pragma unroll
            for (int i = 0; i < 4; ++i)
                if (dsts[i] >= 0)
                    atomicAdd(out + (size_t)dsts[i] * C + t4 * 16 + m, c4[t4][i]);
    }
}

// ---- K6: linear + LayerNorm, in-place on d_out (wave-local rows) ----
__launch_bounds__(256)
__global__ void lin_ln(const float* xin,
                       const unsigned short* __restrict__ WlF,
                       const float* __restrict__ b_lin,
                       const float* __restrict__ gamma,
                       const float* __restrict__ beta,
                       float* out, int nvox) {
    const int tid = threadIdx.x;
    const int lane = tid & 63;
    const int wave = tid >> 6;
    const int m = lane & 15;
    const int krow = lane >> 4;
    const int coff = krow * 8;

    const int rb = blockIdx.x * 128 + wave * 32 + m;
    const int r0 = min(rb, nvox - 1);
    const int r1 = min(rb + 16, nvox - 1);

    auto ldx = [&](int r, int ks) -> short8 {
        const float* p = xin + (size_t)r * C + ks * 32 + coff;
        float4 x0 = *(const float4*)p;
        float4 x1 = *(const float4*)(p + 4);
        short8 v;
        v[0] = (short)f2bf(x0.x); v[1] = (short)f2bf(x0.y);
        v[2] = (short)f2bf(x0.z); v[3] = (short)f2bf(x0.w);
        v[4] = (short)f2bf(x1.x); v[5] = (short)f2bf(x1.y);
        v[6] = (short)f2bf(x1.z); v[7] = (short)f2bf(x1.w);
        return v;
    };
    short8 xa00 = ldx(r0, 0), xa01 = ldx(r0, 1);
    short8 xa10 = ldx(r1, 0), xa11 = ldx(r1, 1);

    f32x4 d0[4], d1[4];
#pragma unroll
    for (int t = 0; t < 4; ++t) {
        d0[t] = (f32x4){0.f, 0.f, 0.f, 0.f};
        d1[t] = (f32x4){0.f, 0.f, 0.f, 0.f};
    }
    const unsigned short* wl = WlF + lane * 8;
#pragma unroll
    for (int t = 0; t < 4; ++t) {
        short8 wb0 = *(const short8*)(wl + t * 1024);
        short8 wb1 = *(const short8*)(wl + t * 1024 + 512);
        d0[t] = __builtin_amdgcn_mfma_f32_16x16x32_bf16(xa00, wb0, d0[t], 0, 0, 0);
        d0[t] = __builtin_amdgcn_mfma_f32_16x16x32_bf16(xa01, wb1, d0[t], 0, 0, 0);
        d1[t] = __builtin_amdgcn_mfma_f32_16x16x32_bf16(xa10, wb0, d1[t], 0, 0, 0);
        d1[t] = __builtin_amdgcn_mfma_f32_16x16x32_bf16(xa11, wb1, d1[t], 0, 0, 0);
    }

    float bl[4], g4[4], bt[4];
#pragma unroll
    for (int t = 0; t < 4; ++t) {
        int col = t * 16 + m;
        bl[t] = b_lin[col];
        g4[t] = gamma[col];
        bt[t] = beta[col];
    }

#pragma unroll
    for (int rbk = 0; rbk < 2; ++rbk) {
        f32x4* d = rbk ? d1 : d0;
        float s1[4], s2[4];
#pragma unroll
        for (int i = 0; i < 4; ++i) {
            float a0 = d[0][i] + bl[0];
            float a1 = d[1][i] + bl[1];
            float a2 = d[2][i] + bl[2];
            float a3 = d[3][i] + bl[3];
            d[0][i] = a0; d[1][i] = a1; d[2][i] = a2; d[3][i] = a3;
            s1[i] = a0 + a1 + a2 + a3;
            s2[i] = a0 * a0 + a1 * a1 + a2 * a2 + a3 * a3;
        }
#pragma unroll
        for (int msk = 1; msk < 16; msk <<= 1) {
#pragma unroll
            for (int i = 0; i < 4; ++i) {
                s1[i] += __shfl_xor(s1[i], msk, 64);
                s2[i] += __shfl_xor(s2[i], msk, 64);
            }
        }
#pragma unroll
        for (int i = 0; i < 4; ++i) {
            float mu = s1[i] * (1.f / 64.f);
            float var = s2[i] * (1.f / 64.f) - mu * mu;
            float rs = rsqrtf(var + EPS);
            int grow = blockIdx.x * 128 + wave * 32 + rbk * 16 + krow * 4 + i;
            if (grow < nvox) {
#pragma unroll
                for (int t = 0; t < 4; ++t)
                    out[(size_t)grow * C + t * 16 + m] = g4[t] * (d[t][i] - mu) * rs + bt[t];
            }
        }
    }
}

extern "C" void kernel_launch(void* const* d_in, const int* in_sizes, int n_in,
                              void* d_out, int out_size, void* d_ws, size_t ws_size,
                              hipStream_t stream) {
    const float* feats = (const float*)d_in[0];
    const int* nb = (const int*)d_in[1];
    const float* Wc = (const float*)d_in[2];
    const float* b_conv = (const float*)d_in[3];
    const float* Wl = (const float*)d_in[4];
    const float* b_lin = (const float*)d_in[5];
    const float* gamma = (const float*)d_in[6];
    const float* beta = (const float*)d_in[7];
    float* out = (float*)d_out;

    const int nvox = in_sizes[0] / C;
    const int nblk_b = (nvox + 255) / 256;

    // ws layout (byte offsets, aligned)
    char* ws = (char*)d_ws;
    unsigned short* feats_bf = (unsigned short*)ws;                    // 2*nvox*64
    size_t off = (size_t)nvox * C * 2;
    unsigned short* WcF = (unsigned short*)(ws + off); off += KOFF * 4096 * 2;
    unsigned short* WlF = (unsigned short*)(ws + off); off += 4096 * 2;
    unsigned short* Z = (unsigned short*)(ws + off);   off += 256;
    off = (off + 255) & ~(size_t)255;
    int* cnt_blk = (int*)(ws + off);                    off += (size_t)nblk_b * 32 * 4;
    off = (off + 255) & ~(size_t)255;
    int* blk_base = (int*)(ws + off);                   off += (size_t)nblk_b * 32 * 4;
    off = (off + 255) & ~(size_t)255;
    int* tot = (int*)(ws + off);                        off += 256;
    off = (off + 255) & ~(size_t)255;
    int2* pairs = (int2*)(ws + off);

    int n4 = (nvox * C) / 4;
    cvt_feats<<<(n4 + 255) / 256, 256, 0, stream>>>(feats, feats_bf, n4);

    int nw = KOFF * 4096 + 4096 + 128;
    cvt_w<<<(nw + 255) / 256, 256, 0, stream>>>(Wc, Wl, WcF, WlF, Z);

    count_pairs<<<nblk_b, 256, 0, stream>>>(nb, cnt_blk, nvox);
    scan_pairs<<<KOFF, 64, 0, stream>>>(cnt_blk, blk_base, tot, nblk_b);
    write_pairs<<<nblk_b, 256, 0, stream>>>(nb, blk_base, pairs, nvox);

    int nblk = (nvox + 127) / 128;
    self_gemm<<<nblk, 256, 0, stream>>>(feats_bf, WcF, b_conv, out, nvox);

    const int NB5 = 2048;
    scatter_conv<<<NB5, 256, 0, stream>>>(feats_bf, WcF, Z, tot, pairs, out, nvox, NB5 * 4);

    lin_ln<<<nblk, 256, 0, stream>>>(out, WlF, b_lin, gamma, beta, out, nvox);
}